// Round 5
// baseline (1007.427 us; speedup 1.0000x reference)
//
#include <hip/hip_runtime.h>

#define N_NODES 50000
#define N_EDGES 600000
#define DIM 128
#define HID 256
#define MR 48            // rows (edges/nodes) per block

typedef float  f32x4  __attribute__((ext_vector_type(4), aligned(16), may_alias));
typedef float  f32x2  __attribute__((ext_vector_type(2), aligned(8),  may_alias));
typedef __bf16 bf16x8 __attribute__((ext_vector_type(8), aligned(16), may_alias));

static __device__ inline f32x4 mfma16x16x32(bf16x8 a, bf16x8 b, f32x4 c) {
    return __builtin_amdgcn_mfma_f32_16x16x32_bf16(a, b, c, 0, 0, 0);
}

static __device__ inline bf16x8 load8_f32_to_bf16(const float* __restrict__ p) {
    f32x4 a = *(const f32x4*)p;
    f32x4 b = *(const f32x4*)(p + 4);
    bf16x8 o;
    o[0] = (__bf16)a[0]; o[1] = (__bf16)a[1]; o[2] = (__bf16)a[2]; o[3] = (__bf16)a[3];
    o[4] = (__bf16)b[0]; o[5] = (__bf16)b[1]; o[6] = (__bf16)b[2]; o[7] = (__bf16)b[3];
    return o;
}

// ---------------------------------------------------------------------------
// Weight pre-pack: W [K, Ncols] fp32 row-major -> MFMA B-fragment order, bf16
// packed[((t*nC + c)*64 + lane)] = { W[t*32 + (lane>>4)*8 + j][c*16 + (lane&15)] }
// ---------------------------------------------------------------------------
__global__ void pack_kernel(const float* __restrict__ W, __bf16* __restrict__ out,
                            int K, int Ncols) {
    int idx = blockIdx.x * 256 + threadIdx.x;
    int total = (K >> 5) * (Ncols >> 4) * 64;
    if (idx >= total) return;
    int lane = idx & 63;
    int tc = idx >> 6;
    int nC = Ncols >> 4;
    int c = tc % nC;
    int t = tc / nC;
    int col = (c << 4) + (lane & 15);
    int k0 = (t << 5) + ((lane >> 4) << 3);
    bf16x8 v;
#pragma unroll
    for (int j = 0; j < 8; ++j) v[j] = (__bf16)W[(k0 + j) * Ncols + col];
    *((bf16x8*)out + idx) = v;
}

// ---------------------------------------------------------------------------
// CSR build: histogram -> exclusive scan -> scatter edge ids per receiver
// ---------------------------------------------------------------------------
__global__ void hist_kernel(const int* __restrict__ eidx, int* __restrict__ counts) {
    int e = blockIdx.x * 256 + threadIdx.x;
    if (e < N_EDGES) {
        int r = eidx[N_EDGES + e];
        r = (r < 0) ? 0 : (r >= N_NODES ? N_NODES - 1 : r);
        atomicAdd(&counts[r], 1);
    }
}

__global__ __launch_bounds__(1024) void scan_kernel(const int* __restrict__ counts,
                                                    int* __restrict__ offsets,
                                                    int* __restrict__ cursor) {
    __shared__ int part[1024];
    const int t = threadIdx.x;
    const int CH = (N_NODES + 1023) / 1024;   // 49
    const int base = t * CH;
    int s = 0;
#pragma unroll 1
    for (int i = 0; i < CH; ++i) {
        int idx = base + i;
        if (idx < N_NODES) s += counts[idx];
    }
    part[t] = s;
    __syncthreads();
    for (int d = 1; d < 1024; d <<= 1) {
        int x = (t >= d) ? part[t - d] : 0;
        __syncthreads();
        part[t] += x;
        __syncthreads();
    }
    int run = part[t] - s;
#pragma unroll 1
    for (int i = 0; i < CH; ++i) {
        int idx = base + i;
        if (idx < N_NODES) {
            offsets[idx] = run;
            cursor[idx]  = run;
            run += counts[idx];
        }
    }
    if (t == 1023) offsets[N_NODES] = run;
}

__global__ void scatter_kernel(const int* __restrict__ eidx,
                               int* __restrict__ cursor, int* __restrict__ eids) {
    int e = blockIdx.x * 256 + threadIdx.x;
    if (e < N_EDGES) {
        int r = eidx[N_EDGES + e];
        r = (r < 0) ? 0 : (r >= N_NODES ? N_NODES - 1 : r);
        int pos = atomicAdd(&cursor[r], 1);
        eids[pos] = e;
    }
}

// ---------------------------------------------------------------------------
// Fused MLP core, 48 rows, 4 waves, N-split, in-register LayerNorm.
// A-tile (48 x K1 bf16, stride ASTRIDE) in lds. Stats at lds + MR*ASTRIDE.
// h' (post-LN/SiLU bf16, stride 528) overwrites the A region after barrier 2.
// Leaves GEMM2 accumulators (rows m*16+g*4+r, cols 32w+16n+l16) in acc2.
// ---------------------------------------------------------------------------
template<int ASTRIDE, int T1>
__device__ inline void mlp_core(char* lds,
                                const bf16x8* __restrict__ pW1,
                                const bf16x8* __restrict__ pW2,
                                const float* __restrict__ b1,
                                const float* __restrict__ g1,
                                const float* __restrict__ be1,
                                f32x4 (&acc2)[3][2]) {
    const int tid = threadIdx.x;
    const int w = tid >> 6;
    const int lane = tid & 63;
    const int l16 = lane & 15;
    const int g = lane >> 4;
    float* stats = (float*)(lds + MR * ASTRIDE);   // [48][8]: (sum,sq) x 4 waves

    // ---- GEMM1: [48,K1] x [K1,256], wave w owns cols [64w, 64w+64) ----
    f32x4 acc[3][4];
#pragma unroll
    for (int m = 0; m < 3; ++m)
#pragma unroll
        for (int n = 0; n < 4; ++n) acc[m][n] = (f32x4){0.f, 0.f, 0.f, 0.f};
#pragma unroll
    for (int t = 0; t < T1; ++t) {
        bf16x8 af[3];
#pragma unroll
        for (int m = 0; m < 3; ++m)
            af[m] = *(const bf16x8*)(lds + (m * 16 + l16) * ASTRIDE + t * 64 + g * 16);
        const bf16x8* bp = pW1 + ((t * 16 + 4 * w) << 6) + lane;
#pragma unroll
        for (int n = 0; n < 4; ++n) {
            bf16x8 bf = bp[n << 6];
#pragma unroll
            for (int m = 0; m < 3; ++m)
                acc[m][n] = mfma16x16x32(af[m], bf, acc[m][n]);
        }
    }

    // ---- bias + per-row stats (in-register) ----
    float b1v[4];
#pragma unroll
    for (int n = 0; n < 4; ++n) b1v[n] = b1[64 * w + 16 * n + l16];
    float sv[3][4], qv[3][4];
#pragma unroll
    for (int m = 0; m < 3; ++m)
#pragma unroll
        for (int r = 0; r < 4; ++r) {
            float s = 0.f, q = 0.f;
#pragma unroll
            for (int n = 0; n < 4; ++n) {
                float x = acc[m][n][r] + b1v[n];
                acc[m][n][r] = x;
                s += x; q += x * x;
            }
            s += __shfl_xor(s, 1); q += __shfl_xor(q, 1);
            s += __shfl_xor(s, 2); q += __shfl_xor(q, 2);
            s += __shfl_xor(s, 4); q += __shfl_xor(q, 4);
            s += __shfl_xor(s, 8); q += __shfl_xor(q, 8);
            sv[m][r] = s; qv[m][r] = q;
        }
    if (l16 == 0) {
#pragma unroll
        for (int m = 0; m < 3; ++m)
#pragma unroll
            for (int r = 0; r < 4; ++r) {
                int row = m * 16 + g * 4 + r;
                *(f32x2*)(stats + row * 8 + w * 2) = (f32x2){sv[m][r], qv[m][r]};
            }
    }
    __syncthreads();   // GEMM1 A-reads done everywhere; stats visible

    // ---- finish LN stats; apply LN + SiLU; write h' (over A region) ----
    float mu[3][4], rs[3][4];
#pragma unroll
    for (int m = 0; m < 3; ++m)
#pragma unroll
        for (int r = 0; r < 4; ++r) {
            int row = m * 16 + g * 4 + r;
            f32x4 a = *(const f32x4*)(stats + row * 8);
            f32x4 b = *(const f32x4*)(stats + row * 8 + 4);
            float S = (a[0] + a[2]) + (b[0] + b[2]);
            float Q = (a[1] + a[3]) + (b[1] + b[3]);
            float mm = S * (1.f / 256.f);
            float vv = fmaxf(Q * (1.f / 256.f) - mm * mm, 0.f);
            mu[m][r] = mm;
            rs[m][r] = rsqrtf(vv + 1e-5f);
        }
    float g1v[4], bev[4];
#pragma unroll
    for (int n = 0; n < 4; ++n) {
        g1v[n] = g1[64 * w + 16 * n + l16];
        bev[n] = be1[64 * w + 16 * n + l16];
    }
#pragma unroll
    for (int m = 0; m < 3; ++m)
#pragma unroll
        for (int n = 0; n < 4; ++n)
#pragma unroll
            for (int r = 0; r < 4; ++r) {
                float x = (acc[m][n][r] - mu[m][r]) * rs[m][r] * g1v[n] + bev[n];
                x = x / (1.f + __expf(-x));   // SiLU
                int row = m * 16 + g * 4 + r;
                int col = 64 * w + 16 * n + l16;
                *(__bf16*)(lds + row * 528 + col * 2) = (__bf16)x;
            }
    __syncthreads();   // h' complete

    // ---- GEMM2: [48,256] x [256,128], wave w owns cols [32w, 32w+32) ----
#pragma unroll
    for (int m = 0; m < 3; ++m)
#pragma unroll
        for (int n = 0; n < 2; ++n) acc2[m][n] = (f32x4){0.f, 0.f, 0.f, 0.f};
#pragma unroll
    for (int t = 0; t < 8; ++t) {
        bf16x8 af[3];
#pragma unroll
        for (int m = 0; m < 3; ++m)
            af[m] = *(const bf16x8*)(lds + (m * 16 + l16) * 528 + t * 64 + g * 16);
        const bf16x8* bp = pW2 + ((t * 8 + 2 * w) << 6) + lane;
#pragma unroll
        for (int n = 0; n < 2; ++n) {
            bf16x8 bf = bp[n << 6];
#pragma unroll
            for (int m = 0; m < 3; ++m)
                acc2[m][n] = mfma16x16x32(af[m], bf, acc2[m][n]);
        }
    }
}

// ---------------------------------------------------------------------------
// Edge kernel: 48 edges/block, 256 threads
// ---------------------------------------------------------------------------
__global__ __launch_bounds__(256) void edge_kernel(
    const float* __restrict__ node, const float* __restrict__ ef,
    const int* __restrict__ eidx,
    const bf16x8* __restrict__ pW1, const bf16x8* __restrict__ pW2,
    const float* __restrict__ b1, const float* __restrict__ g1,
    const float* __restrict__ be1, const float* __restrict__ b2,
    float* __restrict__ out_edges) {
    __shared__ __align__(16) char lds[MR * 784 + MR * 32];   // A/h' + stats = 39168 B
    const int tid = threadIdx.x;
    const int eb = blockIdx.x * MR;

    {   // stage A = [node[snd] | node[rcv] | ef] (bf16): 48 rows x 48 chunks
#pragma unroll
        for (int i = 0; i < 9; ++i) {
            int cid = i * 256 + tid;                 // 0..2303
            int row = (cid * 21846) >> 20;           // cid / 48
            int c = cid - row * 48;
            int e = eb + row;
            int snd = eidx[e], rcv = eidx[N_EDGES + e];
            snd = (snd < 0) ? 0 : (snd >= N_NODES ? N_NODES - 1 : snd);
            rcv = (rcv < 0) ? 0 : (rcv >= N_NODES ? N_NODES - 1 : rcv);
            const float* src = (c < 16) ? (node + (size_t)snd * DIM + (c << 3))
                             : (c < 32) ? (node + (size_t)rcv * DIM + ((c - 16) << 3))
                                        : (ef + (size_t)e * DIM + ((c - 32) << 3));
            *(bf16x8*)(lds + row * 784 + (c << 4)) = load8_f32_to_bf16(src);
        }
    }
    __syncthreads();

    f32x4 acc2[3][2];
    mlp_core<784, 12>(lds, pW1, pW2, b1, g1, be1, acc2);

    {   // epilogue: out = ef + (h' @ W2 + b2), direct from registers
        const int w = tid >> 6, lane = tid & 63;
        const int l16 = lane & 15, g = lane >> 4;
        float b2v[2];
#pragma unroll
        for (int n = 0; n < 2; ++n) b2v[n] = b2[32 * w + 16 * n + l16];
#pragma unroll
        for (int m = 0; m < 3; ++m)
#pragma unroll
            for (int n = 0; n < 2; ++n)
#pragma unroll
                for (int r = 0; r < 4; ++r) {
                    int e = eb + m * 16 + g * 4 + r;
                    int col = 32 * w + 16 * n + l16;
                    size_t off = (size_t)e * DIM + col;
                    out_edges[off] = acc2[m][n][r] + b2v[n] + ef[off];
                }
    }
}

// ---------------------------------------------------------------------------
// Node kernel: 48 nodes/block; CSR-gather aggregate of out_edges
// ---------------------------------------------------------------------------
__global__ __launch_bounds__(256) void node_kernel(
    const float* __restrict__ node, const float* __restrict__ out_edges,
    const int* __restrict__ offsets, const int* __restrict__ eids,
    const bf16x8* __restrict__ pW1, const bf16x8* __restrict__ pW2,
    const float* __restrict__ b1, const float* __restrict__ g1,
    const float* __restrict__ be1, const float* __restrict__ b2,
    float* __restrict__ out_nodes) {
    __shared__ __align__(16) char lds[MR * 528 + MR * 32];   // 26880 B
    const int tid = threadIdx.x;
    const int nb = blockIdx.x * MR;

    {   // stage node part: 48 rows x 16 chunks (768 = 3*256)
#pragma unroll
        for (int i = 0; i < 3; ++i) {
            int cid = i * 256 + tid;
            int row = cid >> 4, c = cid & 15;
            int n = nb + row;
            int nc = (n > N_NODES - 1) ? N_NODES - 1 : n;
            *(bf16x8*)(lds + row * 528 + (c << 4)) =
                load8_f32_to_bf16(node + (size_t)nc * DIM + (c << 3));
        }
    }
    if (tid < 192) {   // CSR aggregate: thread = (row, quarter), 32 cols each
        int row = tid >> 2, q = tid & 3;
        int n = nb + row;
        int nc = (n > N_NODES - 1) ? N_NODES - 1 : n;
        float a[32];
#pragma unroll
        for (int j = 0; j < 32; ++j) a[j] = 0.f;
        int st = offsets[nc], en = offsets[nc + 1];
#pragma unroll 1
        for (int i = st; i < en; ++i) {
            int e = eids[i];
            const float* er = out_edges + (size_t)e * DIM + (q << 5);
#pragma unroll
            for (int k = 0; k < 8; ++k) {
                f32x4 v = *(const f32x4*)(er + (k << 2));
                a[k * 4 + 0] += v[0]; a[k * 4 + 1] += v[1];
                a[k * 4 + 2] += v[2]; a[k * 4 + 3] += v[3];
            }
        }
#pragma unroll
        for (int j = 0; j < 4; ++j) {
            bf16x8 o;
#pragma unroll
            for (int k = 0; k < 8; ++k) o[k] = (__bf16)a[j * 8 + k];
            *(bf16x8*)(lds + row * 528 + ((16 + (q << 2) + j) << 4)) = o;
        }
    }
    __syncthreads();

    f32x4 acc2[3][2];
    mlp_core<528, 8>(lds, pW1, pW2, b1, g1, be1, acc2);

    {   // epilogue: out = node + (h' @ W2 + b2), guarded
        const int w = tid >> 6, lane = tid & 63;
        const int l16 = lane & 15, g = lane >> 4;
        float b2v[2];
#pragma unroll
        for (int n = 0; n < 2; ++n) b2v[n] = b2[32 * w + 16 * n + l16];
#pragma unroll
        for (int m = 0; m < 3; ++m)
#pragma unroll
            for (int n = 0; n < 2; ++n)
#pragma unroll
                for (int r = 0; r < 4; ++r) {
                    int nd = nb + m * 16 + g * 4 + r;
                    if (nd < N_NODES) {
                        int col = 32 * w + 16 * n + l16;
                        size_t off = (size_t)nd * DIM + col;
                        out_nodes[off] = acc2[m][n][r] + b2v[n] + node[off];
                    }
                }
    }
}

// ---------------------------------------------------------------------------
extern "C" void kernel_launch(void* const* d_in, const int* in_sizes, int n_in,
                              void* d_out, int out_size, void* d_ws, size_t ws_size,
                              hipStream_t stream) {
    const float* node  = (const float*)d_in[0];
    const float* ef    = (const float*)d_in[1];
    const int*   eidx  = (const int*)d_in[2];
    const float* eW1   = (const float*)d_in[3];
    const float* eb1   = (const float*)d_in[4];
    const float* eg1   = (const float*)d_in[5];
    const float* ebt1  = (const float*)d_in[6];
    const float* eW2   = (const float*)d_in[7];
    const float* eb2   = (const float*)d_in[8];
    const float* nW1   = (const float*)d_in[9];
    const float* nb1   = (const float*)d_in[10];
    const float* ng1   = (const float*)d_in[11];
    const float* nbt1  = (const float*)d_in[12];
    const float* nW2   = (const float*)d_in[13];
    const float* nb2   = (const float*)d_in[14];

    char* ws = (char*)d_ws;
    int* counts  = (int*)ws;
    int* offsets = counts + 50016;
    int* cursor  = offsets + 50016;
    int* eids    = cursor + 50016;
    char* wbase = (char*)(eids + 600064);
    __bf16* peW1 = (__bf16*)(((uintptr_t)wbase + 255) & ~(uintptr_t)255);
    __bf16* peW2 = peW1 + 384 * 256;
    __bf16* pnW1 = peW2 + 256 * 128;
    __bf16* pnW2 = pnW1 + 256 * 256;

    hipMemsetAsync(counts, 0, 50000 * sizeof(int), stream);
    pack_kernel<<<48, 256, 0, stream>>>(eW1, peW1, 384, 256);
    pack_kernel<<<16, 256, 0, stream>>>(eW2, peW2, 256, 128);
    pack_kernel<<<32, 256, 0, stream>>>(nW1, pnW1, 256, 256);
    pack_kernel<<<16, 256, 0, stream>>>(nW2, pnW2, 256, 128);

    hist_kernel<<<(N_EDGES + 255) / 256, 256, 0, stream>>>(eidx, counts);
    scan_kernel<<<1, 1024, 0, stream>>>(counts, offsets, cursor);
    scatter_kernel<<<(N_EDGES + 255) / 256, 256, 0, stream>>>(eidx, cursor, eids);

    float* out_nodes = (float*)d_out;
    float* out_edges = out_nodes + (size_t)N_NODES * DIM;

    edge_kernel<<<N_EDGES / MR, 256, 0, stream>>>(
        node, ef, eidx, (const bf16x8*)peW1, (const bf16x8*)peW2,
        eb1, eg1, ebt1, eb2, out_edges);
    node_kernel<<<(N_NODES + MR - 1) / MR, 256, 0, stream>>>(
        node, out_edges, offsets, eids, (const bf16x8*)pnW1, (const bf16x8*)pnW2,
        nb1, ng1, nbt1, nb2, out_nodes);
}

// Round 6
// 653.527 us; speedup vs baseline: 1.5415x; 1.5415x over previous
//
#include <hip/hip_runtime.h>

#define N_NODES 50000
#define N_EDGES 600000
#define DIM 128
#define HID 256
#define MR 32            // rows (edges/nodes) per block

typedef float  f32x4  __attribute__((ext_vector_type(4), aligned(16), may_alias));
typedef float  f32x2  __attribute__((ext_vector_type(2), aligned(8),  may_alias));
typedef __bf16 bf16x8 __attribute__((ext_vector_type(8), aligned(16), may_alias));

static __device__ inline f32x4 mfma16x16x32(bf16x8 a, bf16x8 b, f32x4 c) {
    return __builtin_amdgcn_mfma_f32_16x16x32_bf16(a, b, c, 0, 0, 0);
}

static __device__ inline bf16x8 load8_f32_to_bf16(const float* __restrict__ p) {
    f32x4 a = *(const f32x4*)p;
    f32x4 b = *(const f32x4*)(p + 4);
    bf16x8 o;
    o[0] = (__bf16)a[0]; o[1] = (__bf16)a[1]; o[2] = (__bf16)a[2]; o[3] = (__bf16)a[3];
    o[4] = (__bf16)b[0]; o[5] = (__bf16)b[1]; o[6] = (__bf16)b[2]; o[7] = (__bf16)b[3];
    return o;
}

// ---------------------------------------------------------------------------
// Weight pre-pack: W [K, Ncols] fp32 row-major -> MFMA B-fragment order, bf16
// packed[((t*nC + c)*64 + lane)] = { W[t*32 + (lane>>4)*8 + j][c*16 + (lane&15)] }
// ---------------------------------------------------------------------------
__global__ void pack_kernel(const float* __restrict__ W, __bf16* __restrict__ out,
                            int K, int Ncols) {
    int idx = blockIdx.x * 256 + threadIdx.x;
    int total = (K >> 5) * (Ncols >> 4) * 64;
    if (idx >= total) return;
    int lane = idx & 63;
    int tc = idx >> 6;
    int nC = Ncols >> 4;
    int c = tc % nC;
    int t = tc / nC;
    int col = (c << 4) + (lane & 15);
    int k0 = (t << 5) + ((lane >> 4) << 3);
    bf16x8 v;
#pragma unroll
    for (int j = 0; j < 8; ++j) v[j] = (__bf16)W[(k0 + j) * Ncols + col];
    *((bf16x8*)out + idx) = v;
}

// ---------------------------------------------------------------------------
// CSR build: histogram -> exclusive scan -> scatter edge ids per receiver
// ---------------------------------------------------------------------------
__global__ void hist_kernel(const int* __restrict__ eidx, int* __restrict__ counts) {
    int e = blockIdx.x * 256 + threadIdx.x;
    if (e < N_EDGES) {
        int r = eidx[N_EDGES + e];
        r = (r < 0) ? 0 : (r >= N_NODES ? N_NODES - 1 : r);
        atomicAdd(&counts[r], 1);
    }
}

__global__ __launch_bounds__(1024) void scan_kernel(const int* __restrict__ counts,
                                                    int* __restrict__ offsets,
                                                    int* __restrict__ cursor) {
    __shared__ int part[1024];
    const int t = threadIdx.x;
    const int CH = (N_NODES + 1023) / 1024;   // 49
    const int base = t * CH;
    int s = 0;
#pragma unroll 1
    for (int i = 0; i < CH; ++i) {
        int idx = base + i;
        if (idx < N_NODES) s += counts[idx];
    }
    part[t] = s;
    __syncthreads();
    for (int d = 1; d < 1024; d <<= 1) {
        int x = (t >= d) ? part[t - d] : 0;
        __syncthreads();
        part[t] += x;
        __syncthreads();
    }
    int run = part[t] - s;
#pragma unroll 1
    for (int i = 0; i < CH; ++i) {
        int idx = base + i;
        if (idx < N_NODES) {
            offsets[idx] = run;
            cursor[idx]  = run;
            run += counts[idx];
        }
    }
    if (t == 1023) offsets[N_NODES] = run;
}

__global__ void scatter_kernel(const int* __restrict__ eidx,
                               int* __restrict__ cursor, int* __restrict__ eids) {
    int e = blockIdx.x * 256 + threadIdx.x;
    if (e < N_EDGES) {
        int r = eidx[N_EDGES + e];
        r = (r < 0) ? 0 : (r >= N_NODES ? N_NODES - 1 : r);
        int pos = atomicAdd(&cursor[r], 1);
        eids[pos] = e;
    }
}

// ---------------------------------------------------------------------------
// Fused MLP core, 32 rows, 4 waves (4-way N-split), in-register LayerNorm.
// A-tile (32 x K1 bf16, stride ASTRIDE) in lds; stats at lds + 32*ASTRIDE.
// h' (post-LN/SiLU bf16, stride 528) overwrites the A region after the stats
// barrier (all GEMM1 A-reads complete by then).
// Leaves GEMM2 accum (row m*16+g*4+r, col 32w+16n+l16) in acc2.
// ---------------------------------------------------------------------------
template<int ASTRIDE, int T1>
__device__ inline void mlp_core(char* lds,
                                const bf16x8* __restrict__ pW1,
                                const bf16x8* __restrict__ pW2,
                                const float* __restrict__ b1,
                                const float* __restrict__ g1,
                                const float* __restrict__ be1,
                                f32x4 (&acc2)[2][2]) {
    const int tid = threadIdx.x;
    const int w = tid >> 6;
    const int lane = tid & 63;
    const int l16 = lane & 15;
    const int g = lane >> 4;
    float* stats = (float*)(lds + 32 * ASTRIDE);   // [32][8]: (sum,sq) x 4 waves

    // ---- GEMM1: [32,K1] x [K1,256], wave w owns cols [64w, 64w+64) ----
    f32x4 acc[2][4];
#pragma unroll
    for (int m = 0; m < 2; ++m)
#pragma unroll
        for (int n = 0; n < 4; ++n) acc[m][n] = (f32x4){0.f, 0.f, 0.f, 0.f};
#pragma unroll
    for (int t = 0; t < T1; ++t) {
        bf16x8 af[2];
#pragma unroll
        for (int m = 0; m < 2; ++m)
            af[m] = *(const bf16x8*)(lds + (m * 16 + l16) * ASTRIDE + t * 64 + g * 16);
        const bf16x8* bp = pW1 + ((t * 16 + 4 * w) << 6) + lane;
#pragma unroll
        for (int n = 0; n < 4; ++n) {
            bf16x8 bf = bp[n << 6];
#pragma unroll
            for (int m = 0; m < 2; ++m)
                acc[m][n] = mfma16x16x32(af[m], bf, acc[m][n]);
        }
    }

    // ---- bias + per-row stats (in-register, 16-lane reduce) ----
    float b1v[4];
#pragma unroll
    for (int n = 0; n < 4; ++n) b1v[n] = b1[64 * w + 16 * n + l16];
#pragma unroll
    for (int m = 0; m < 2; ++m)
#pragma unroll
        for (int r = 0; r < 4; ++r) {
            float s = 0.f, q = 0.f;
#pragma unroll
            for (int n = 0; n < 4; ++n) {
                float x = acc[m][n][r] + b1v[n];
                acc[m][n][r] = x;
                s += x; q += x * x;
            }
            s += __shfl_xor(s, 1); q += __shfl_xor(q, 1);
            s += __shfl_xor(s, 2); q += __shfl_xor(q, 2);
            s += __shfl_xor(s, 4); q += __shfl_xor(q, 4);
            s += __shfl_xor(s, 8); q += __shfl_xor(q, 8);
            if (l16 == 0) {
                int row = m * 16 + g * 4 + r;
                *(f32x2*)(stats + row * 8 + w * 2) = (f32x2){s, q};
            }
        }
    __syncthreads();   // GEMM1 A-reads done everywhere; stats visible

    // ---- finish LN stats; apply LN + SiLU; write h' (over A region) ----
    float mu[2][4], rs[2][4];
#pragma unroll
    for (int m = 0; m < 2; ++m)
#pragma unroll
        for (int r = 0; r < 4; ++r) {
            int row = m * 16 + g * 4 + r;
            f32x4 a = *(const f32x4*)(stats + row * 8);
            f32x4 b = *(const f32x4*)(stats + row * 8 + 4);
            float S = (a[0] + a[2]) + (b[0] + b[2]);
            float Q = (a[1] + a[3]) + (b[1] + b[3]);
            float mm = S * (1.f / 256.f);
            float vv = fmaxf(Q * (1.f / 256.f) - mm * mm, 0.f);
            mu[m][r] = mm;
            rs[m][r] = rsqrtf(vv + 1e-5f);
        }
    float g1v[4], bev[4];
#pragma unroll
    for (int n = 0; n < 4; ++n) {
        g1v[n] = g1[64 * w + 16 * n + l16];
        bev[n] = be1[64 * w + 16 * n + l16];
    }
#pragma unroll
    for (int m = 0; m < 2; ++m)
#pragma unroll
        for (int n = 0; n < 4; ++n)
#pragma unroll
            for (int r = 0; r < 4; ++r) {
                float x = (acc[m][n][r] - mu[m][r]) * rs[m][r] * g1v[n] + bev[n];
                x = x / (1.f + __expf(-x));   // SiLU
                int row = m * 16 + g * 4 + r;
                int col = 64 * w + 16 * n + l16;
                *(__bf16*)(lds + row * 528 + col * 2) = (__bf16)x;
            }
    __syncthreads();   // h' complete

    // ---- GEMM2: [32,256] x [256,128], wave w owns cols [32w, 32w+32) ----
#pragma unroll
    for (int m = 0; m < 2; ++m)
#pragma unroll
        for (int n = 0; n < 2; ++n) acc2[m][n] = (f32x4){0.f, 0.f, 0.f, 0.f};
#pragma unroll
    for (int t = 0; t < 8; ++t) {
        bf16x8 af[2];
#pragma unroll
        for (int m = 0; m < 2; ++m)
            af[m] = *(const bf16x8*)(lds + (m * 16 + l16) * 528 + t * 64 + g * 16);
        const bf16x8* bp = pW2 + ((t * 8 + 2 * w) << 6) + lane;
#pragma unroll
        for (int n = 0; n < 2; ++n) {
            bf16x8 bf = bp[n << 6];
#pragma unroll
            for (int m = 0; m < 2; ++m)
                acc2[m][n] = mfma16x16x32(af[m], bf, acc2[m][n]);
        }
    }
}

// ---------------------------------------------------------------------------
// Edge kernel: 32 edges/block, 256 threads, 5 blocks/CU target
// ---------------------------------------------------------------------------
__global__ __launch_bounds__(256, 5) void edge_kernel(
    const float* __restrict__ node, const float* __restrict__ ef,
    const int* __restrict__ eidx,
    const bf16x8* __restrict__ pW1, const bf16x8* __restrict__ pW2,
    const float* __restrict__ b1, const float* __restrict__ g1,
    const float* __restrict__ be1, const float* __restrict__ b2,
    float* __restrict__ out_edges) {
    __shared__ __align__(16) char lds[MR * 784 + MR * 32];   // 26112 B
    const int tid = threadIdx.x;
    const int eb = blockIdx.x * MR;

    {   // stage A = [node[snd] | node[rcv] | ef] (bf16): row = tid>>3, 6 chunks
        int row = tid >> 3, l8 = tid & 7;
        int e = eb + row;
        int snd = eidx[e], rcv = eidx[N_EDGES + e];
        snd = (snd < 0) ? 0 : (snd >= N_NODES ? N_NODES - 1 : snd);
        rcv = (rcv < 0) ? 0 : (rcv >= N_NODES ? N_NODES - 1 : rcv);
        const float* ps = node + (size_t)snd * DIM;
        const float* pr = node + (size_t)rcv * DIM;
        const float* pe = ef + (size_t)e * DIM;
#pragma unroll
        for (int i = 0; i < 6; ++i) {
            int c = l8 + (i << 3);
            const float* src = (c < 16) ? (ps + (c << 3))
                             : (c < 32) ? (pr + ((c - 16) << 3))
                                        : (pe + ((c - 32) << 3));
            *(bf16x8*)(lds + row * 784 + (c << 4)) = load8_f32_to_bf16(src);
        }
    }
    __syncthreads();

    f32x4 acc2[2][2];
    mlp_core<784, 12>(lds, pW1, pW2, b1, g1, be1, acc2);

    {   // epilogue: out = ef + (h' @ W2 + b2), direct from registers
        const int w = tid >> 6, lane = tid & 63;
        const int l16 = lane & 15, g = lane >> 4;
        float b2v[2];
#pragma unroll
        for (int n = 0; n < 2; ++n) b2v[n] = b2[32 * w + 16 * n + l16];
#pragma unroll
        for (int m = 0; m < 2; ++m)
#pragma unroll
            for (int n = 0; n < 2; ++n)
#pragma unroll
                for (int r = 0; r < 4; ++r) {
                    int e = eb + m * 16 + g * 4 + r;
                    int col = 32 * w + 16 * n + l16;
                    size_t off = (size_t)e * DIM + col;
                    out_edges[off] = acc2[m][n][r] + b2v[n] + ef[off];
                }
    }
}

// ---------------------------------------------------------------------------
// Node kernel: 32 nodes/block; CSR-gather aggregate of out_edges
// ---------------------------------------------------------------------------
__global__ __launch_bounds__(256, 5) void node_kernel(
    const float* __restrict__ node, const float* __restrict__ out_edges,
    const int* __restrict__ offsets, const int* __restrict__ eids,
    const bf16x8* __restrict__ pW1, const bf16x8* __restrict__ pW2,
    const float* __restrict__ b1, const float* __restrict__ g1,
    const float* __restrict__ be1, const float* __restrict__ b2,
    float* __restrict__ out_nodes) {
    __shared__ __align__(16) char lds[MR * 528 + MR * 32];   // 17920 B
    const int tid = threadIdx.x;
    const int nb = blockIdx.x * MR;

    {   // stage node_input = [node[n] | csr aggregate] -> bf16
        int row = tid >> 3, l8 = tid & 7;
        int n = nb + row;
        int nc = (n > N_NODES - 1) ? N_NODES - 1 : n;
        // first 128 cols: node features (chunks l8, l8+8)
#pragma unroll
        for (int i = 0; i < 2; ++i) {
            int c = l8 + (i << 3);
            *(bf16x8*)(lds + row * 528 + (c << 4)) =
                load8_f32_to_bf16(node + (size_t)nc * DIM + (c << 3));
        }
        // last 128 cols: aggregate; lane owns 16 contiguous cols [l8*16, +16)
        float a[16];
#pragma unroll
        for (int j = 0; j < 16; ++j) a[j] = 0.f;
        int st = offsets[nc], en = offsets[nc + 1];
#pragma unroll 1
        for (int i = st; i < en; ++i) {
            int e = eids[i];
            const float* er = out_edges + (size_t)e * DIM + (l8 << 4);
#pragma unroll
            for (int k = 0; k < 4; ++k) {
                f32x4 v = *(const f32x4*)(er + (k << 2));
                a[k * 4 + 0] += v[0]; a[k * 4 + 1] += v[1];
                a[k * 4 + 2] += v[2]; a[k * 4 + 3] += v[3];
            }
        }
        bf16x8 o0, o1;
#pragma unroll
        for (int j = 0; j < 8; ++j) { o0[j] = (__bf16)a[j]; o1[j] = (__bf16)a[8 + j]; }
        int cbase = 16 + (l8 << 1);
        *(bf16x8*)(lds + row * 528 + (cbase << 4)) = o0;
        *(bf16x8*)(lds + row * 528 + ((cbase + 1) << 4)) = o1;
    }
    __syncthreads();

    f32x4 acc2[2][2];
    mlp_core<528, 8>(lds, pW1, pW2, b1, g1, be1, acc2);

    {   // epilogue: out = node + (h' @ W2 + b2), guarded
        const int w = tid >> 6, lane = tid & 63;
        const int l16 = lane & 15, g = lane >> 4;
        float b2v[2];
#pragma unroll
        for (int n = 0; n < 2; ++n) b2v[n] = b2[32 * w + 16 * n + l16];
#pragma unroll
        for (int m = 0; m < 2; ++m)
#pragma unroll
            for (int n = 0; n < 2; ++n)
#pragma unroll
                for (int r = 0; r < 4; ++r) {
                    int nd = nb + m * 16 + g * 4 + r;
                    if (nd < N_NODES) {
                        int col = 32 * w + 16 * n + l16;
                        size_t off = (size_t)nd * DIM + col;
                        out_nodes[off] = acc2[m][n][r] + b2v[n] + node[off];
                    }
                }
    }
}

// ---------------------------------------------------------------------------
extern "C" void kernel_launch(void* const* d_in, const int* in_sizes, int n_in,
                              void* d_out, int out_size, void* d_ws, size_t ws_size,
                              hipStream_t stream) {
    const float* node  = (const float*)d_in[0];
    const float* ef    = (const float*)d_in[1];
    const int*   eidx  = (const int*)d_in[2];
    const float* eW1   = (const float*)d_in[3];
    const float* eb1   = (const float*)d_in[4];
    const float* eg1   = (const float*)d_in[5];
    const float* ebt1  = (const float*)d_in[6];
    const float* eW2   = (const float*)d_in[7];
    const float* eb2   = (const float*)d_in[8];
    const float* nW1   = (const float*)d_in[9];
    const float* nb1   = (const float*)d_in[10];
    const float* ng1   = (const float*)d_in[11];
    const float* nbt1  = (const float*)d_in[12];
    const float* nW2   = (const float*)d_in[13];
    const float* nb2   = (const float*)d_in[14];

    char* ws = (char*)d_ws;
    int* counts  = (int*)ws;
    int* offsets = counts + 50016;
    int* cursor  = offsets + 50016;
    int* eids    = cursor + 50016;
    char* wbase = (char*)(eids + 600064);
    __bf16* peW1 = (__bf16*)(((uintptr_t)wbase + 255) & ~(uintptr_t)255);
    __bf16* peW2 = peW1 + 384 * 256;
    __bf16* pnW1 = peW2 + 256 * 128;
    __bf16* pnW2 = pnW1 + 256 * 256;

    hipMemsetAsync(counts, 0, 50000 * sizeof(int), stream);
    pack_kernel<<<48, 256, 0, stream>>>(eW1, peW1, 384, 256);
    pack_kernel<<<16, 256, 0, stream>>>(eW2, peW2, 256, 128);
    pack_kernel<<<32, 256, 0, stream>>>(nW1, pnW1, 256, 256);
    pack_kernel<<<16, 256, 0, stream>>>(nW2, pnW2, 256, 128);

    hist_kernel<<<(N_EDGES + 255) / 256, 256, 0, stream>>>(eidx, counts);
    scan_kernel<<<1, 1024, 0, stream>>>(counts, offsets, cursor);
    scatter_kernel<<<(N_EDGES + 255) / 256, 256, 0, stream>>>(eidx, cursor, eids);

    float* out_nodes = (float*)d_out;
    float* out_edges = out_nodes + (size_t)N_NODES * DIM;

    edge_kernel<<<N_EDGES / MR, 256, 0, stream>>>(
        node, ef, eidx, (const bf16x8*)peW1, (const bf16x8*)peW2,
        eb1, eg1, ebt1, eb2, out_edges);
    node_kernel<<<(N_NODES + MR - 1) / MR, 256, 0, stream>>>(
        node, out_edges, offsets, eids, (const bf16x8*)pnW1, (const bf16x8*)pnW2,
        nb1, ng1, nbt1, nb2, out_nodes);
}